// Round 15
// baseline (90.644 us; speedup 1.0000x reference)
//
#include <hip/hip_runtime.h>
#include <hip/hip_fp16.h>

#define HH 64
#define WW 64
#define TT 16
#define NPIX (HH * WW * TT)   // 65536
#define HALO_H 8              // tile 2 + 2*3
#define HALO_W 10             // tile 4 + 2*3
#define HWPOS (HALO_H * HALO_W)   // 80 halo (h,w) positions
// LDS strides: gui/img stored f16 at row stride 16 halves (half2 reads are
// 2-way bank aliased = free); est/var f32 at row stride 18 floats (18*row
// mod 32 spans 8 distinct group offsets -> <=2-way on b64 reads).
#define GUI_CH 1280           // 80*16 halves
#define EV_ROW 18
#define EV_CH  1440           // 80*18 floats
#define IMG_CH 1280           // 80*16 halves
#define EV_BYTES  (6 * EV_CH * 4)    // 34560
#define GUI_BYTES (9 * GUI_CH * 2)   // 23040
#define IMG_BYTES (3 * IMG_CH * 2)   //  7680
#define SMEM_BYTES (EV_BYTES + GUI_BYTES + IMG_BYTES)   // 65280 B = 63.75 KB

// lane i <- lane i-1 within 16-lane DPP rows (row_shr:1), 0-fill at row start.
__device__ __forceinline__ float dpp_up1(float x) {
    return __int_as_float(__builtin_amdgcn_update_dpp(
        0, __float_as_int(x), 0x111, 0xF, 0xF, true));
}
// lane i <- lane i+1 within 16-lane DPP rows (row_shl:1), 0-fill at row end.
__device__ __forceinline__ float dpp_dn1(float x) {
    return __int_as_float(__builtin_amdgcn_update_dpp(
        0, __float_as_int(x), 0x101, 0xF, 0xF, true));
}

// Max-occupancy config: 512 blocks x 1024 thr, LDS 63.75 KB -> 2 blocks/CU
// co-resident -> 32 waves/CU = 8 waves/SIMD (vs 4 for R9's 28.7us best).
// K-loop touches ONLY LDS (R12 proved fetch goes compulsory); gui+img f16
// (smooth paths), est/var f32 (membership bit-exact). K=2 + DPP body is
// R9's, which compiled to 32 VGPR at 1024 thr (under the 64-VGPR cap that
// killed the K=4 body in R11/R13). Membership simplified (case-verified):
// mem = (d2==0) | (d2 < G2*V & vce!=0 & vnv!=0).
__global__ __launch_bounds__(1024, 8) void statdenoise_kernel(
    const float* __restrict__ img,
    const float* __restrict__ gui,
    const float* __restrict__ est,
    const float* __restrict__ var,
    float* __restrict__ out)
{
    __shared__ __align__(16) char smemRaw[SMEM_BYTES];
    float*  evS  = (float*)smemRaw;                          // [6][80][18] f32
    __half* guiS = (__half*)(smemRaw + EV_BYTES);            // [9][80][16] f16
    __half* imgS = (__half*)(smemRaw + EV_BYTES + GUI_BYTES);// [3][80][16] f16

    const float SIG[9] = {0.1f, 0.1f, 0.1f, 50.0f, 50.0f, 50.0f, 10.0f, 10.0f, 10.0f};
    const float G2 = 2.907f * 2.907f;   // gamma^2

    const int tid  = threadIdx.x;
    const int lane = tid & 63;
    const int s    = tid >> 6;      // wave id == column-split 0..15
    const int tg   = lane & 7;      // t-group 0..7
    const int hwl  = lane >> 3;     // tile pixel 0..7 (2h x 4w)
    const int t0   = tg * 2;        // owns t0, t0+1
    const int h0   = (blockIdx.x >> 4) << 1;   // 32 h-tiles x 2 rows
    const int w0   = (blockIdx.x & 15) << 2;   // 16 w-tiles x 4 cols

    // ---- stage 18 channels of the 8x10x16 halo (edge-clamped; OOB pairs
    //      masked later by inb — same semantics as the clamped loads) ----
#pragma unroll
    for (int rep = 0; rep < 2; ++rep) {
        const int q = tid + rep * 1024;
        if (q < HWPOS * TT) {
            const int t   = q & 15;
            const int hwq = q >> 4;                  // 0..79
            const int hq  = (hwq * 205) >> 11;       // exact /10 for hwq<1024
            const int wq  = hwq - hq * 10;
            const int hs  = min(max(h0 - 3 + hq, 0), HH - 1);
            const int ws  = min(max(w0 - 3 + wq, 0), WW - 1);
            const int g   = (((hs << 6) + ws) << 4) + t;
#pragma unroll
            for (int c = 0; c < 9; ++c)
                guiS[c * GUI_CH + hwq * 16 + t] = __float2half(gui[c * NPIX + g]);
#pragma unroll
            for (int c = 0; c < 3; ++c) {
                evS[c       * EV_CH + hwq * EV_ROW + t] = est[c * NPIX + g];
                evS[(3 + c) * EV_CH + hwq * EV_ROW + t] = var[c * NPIX + g];
                imgS[c * IMG_CH + hwq * 16 + t] = __float2half(img[c * NPIX + g]);
            }
        }
    }
    __syncthreads();

    const int th = hwl >> 2, tw = hwl & 3;     // tile-local pixel (2h x 4w)
    const int hg = h0 + th,  wg = w0 + tw;     // global pixel

    // center values from LDS
    const int rowc = (th + 3) * 10 + (tw + 3);
    float2 gc[9];
#pragma unroll
    for (int c = 0; c < 9; ++c)
        gc[c] = __half22float2(*(const __half2*)&guiS[c * GUI_CH + rowc * 16 + t0]);
    float2 ec[3], vc[3];
#pragma unroll
    for (int c = 0; c < 3; ++c) {
        ec[c] = *(const float2*)&evS[c       * EV_CH + rowc * EV_ROW + t0];
        vc[c] = *(const float2*)&evS[(3 + c) * EV_CH + rowc * EV_ROW + t0];
    }

    const bool vLo = (t0 != 0);    // dt=-1 for e=0; also masks DPP boundary garbage
    const bool vHi = (t0 != 14);   // dt=+1 for e=1; also masks DPP boundary garbage

    float acc[2][4] = {};   // per owned t: {r,g,b,wsum}

    int dh = s / 7 - 3, dw = s % 7 - 3;   // column r = s, then += 16
    for (int r = s; r < 49; r += 16) {
        // halo coords always in range: th+dh+3 in [0,7], tw+dw+3 in [0,9]
        const int rowb = (th + dh + 3) * 10 + (tw + dw + 3);
        const bool inb = ((unsigned)(hg + dh) < (unsigned)HH) &
                         ((unsigned)(wg + dw) < (unsigned)WW);

        // ---- bilateral over 9 guidance channels, 6 (e,dt) pairs ----
        float sb[2][3] = {};
#pragma unroll
        for (int c = 0; c < 9; ++c) {
            float2 m = __half22float2(*(const __half2*)&guiS[c * GUI_CH + rowb * 16 + t0]);
            float nv[4] = {dpp_up1(m.y), m.x, m.y, dpp_dn1(m.x)};   // t0-1..t0+2
#pragma unroll
            for (int e = 0; e < 2; ++e) {
                float ce = e ? gc[c].y : gc[c].x;
#pragma unroll
                for (int k = 0; k < 3; ++k) {
                    float d = ce - nv[e + k];
                    sb[e][k] = fmaf(d * d, SIG[c], sb[e][k]);
                }
            }
        }

        // ---- membership (division-free Welch t-test, simplified) ----
        // mem = (d2==0) | (d2 < G2*V & vce!=0 & vnv!=0). Case-verified vs
        // reference (incl. v==0 kills and num==den==0 -> 0.5 -> member).
        bool mem[2][3] = {{true, true, true}, {true, true, true}};
#pragma unroll
        for (int c = 0; c < 3; ++c) {
            float2 em = *(const float2*)&evS[c       * EV_CH + rowb * EV_ROW + t0];
            float2 vm = *(const float2*)&evS[(3 + c) * EV_CH + rowb * EV_ROW + t0];
            float env[4] = {dpp_up1(em.y), em.x, em.y, dpp_dn1(em.x)};
            float vnv[4] = {dpp_up1(vm.y), vm.x, vm.y, dpp_dn1(vm.x)};
#pragma unroll
            for (int e = 0; e < 2; ++e) {
                float ece = e ? ec[c].y : ec[c].x;
                float vce = e ? vc[c].y : vc[c].x;
#pragma unroll
                for (int k = 0; k < 3; ++k) {
                    float d  = ece - env[e + k];
                    float d2 = d * d;
                    float V  = vce + vnv[e + k];
                    bool ok = (d2 == 0.f) |
                              ((d2 < G2 * V) & !((vce == 0.f) | (vnv[e + k] == 0.f)));
                    mem[e][k] = mem[e][k] & ok;
                }
            }
        }

        // ---- weights ----
        float wt[2][3];
#pragma unroll
        for (int e = 0; e < 2; ++e) {
#pragma unroll
            for (int k = 0; k < 3; ++k) {
                bool ok = inb && mem[e][k];
                if (e == 0 && k == 0) ok = ok && vLo;   // tt = t0-1
                if (e == 1 && k == 2) ok = ok && vHi;   // tt = t0+2
                wt[e][k] = ok ? __expf(-0.5f * sb[e][k]) : 0.f;
            }
        }

        // ---- accumulate image (from LDS, f16->f32) ----
#pragma unroll
        for (int c = 0; c < 3; ++c) {
            float2 im = __half22float2(*(const __half2*)&imgS[c * IMG_CH + rowb * 16 + t0]);
            float iv[4] = {dpp_up1(im.y), im.x, im.y, dpp_dn1(im.x)};
#pragma unroll
            for (int e = 0; e < 2; ++e) {
                acc[e][c] = fmaf(wt[e][0], iv[e],
                            fmaf(wt[e][1], iv[e + 1],
                            fmaf(wt[e][2], iv[e + 2], acc[e][c])));
            }
        }
#pragma unroll
        for (int e = 0; e < 2; ++e)
            acc[e][3] += wt[e][0] + wt[e][1] + wt[e][2];

        dw += 16;
        while (dw > 3) { dw -= 7; ++dh; }
    }

    // ---- combine the 16 splits (alias staging LDS after all reads done) ----
    __syncthreads();
    float4* red = (float4*)smemRaw;       // 16*64*2 float4 = 32 KB < 63.75 KB
    red[(s * 64 + lane) * 2 + 0] = make_float4(acc[0][0], acc[0][1], acc[0][2], acc[0][3]);
    red[(s * 64 + lane) * 2 + 1] = make_float4(acc[1][0], acc[1][1], acc[1][2], acc[1][3]);
    __syncthreads();

    if (tid < 128) {
        const int hw_ = tid >> 4;           // tile pixel 0..7
        const int t_  = tid & 15;           // t 0..15
        const int tg_ = t_ >> 1, e_ = t_ & 1;
        const int li  = hw_ * 8 + tg_;      // lane that owns this (hw, t0) group
        float4 sum = make_float4(0.f, 0.f, 0.f, 0.f);
#pragma unroll
        for (int q = 0; q < 16; ++q) {
            float4 v = red[(q * 64 + li) * 2 + e_];
            sum.x += v.x; sum.y += v.y; sum.z += v.z; sum.w += v.w;
        }
        const int th_ = hw_ >> 2, tw_ = hw_ & 3;
        const int px = ((((h0 + th_) << 6) + (w0 + tw_)) << 4) + t_;
        const float inv = 1.f / sum.w;      // wsum >= 1 (center weight == 1)
        out[0 * NPIX + px] = sum.x * inv;
        out[1 * NPIX + px] = sum.y * inv;
        out[2 * NPIX + px] = sum.z * inv;
    }
}

extern "C" void kernel_launch(void* const* d_in, const int* in_sizes, int n_in,
                              void* d_out, int out_size, void* d_ws, size_t ws_size,
                              hipStream_t stream) {
    const float* img = (const float*)d_in[0];
    const float* gui = (const float*)d_in[1];
    const float* est = (const float*)d_in[2];
    const float* var = (const float*)d_in[3];
    float* out = (float*)d_out;

    dim3 grid(512);     // 32x16 tiles of 2x4x16; 2 blocks/CU (LDS 63.75 KB)
    dim3 block(1024);   // 16 waves = 16 column-splits; wave covers whole tile
    statdenoise_kernel<<<grid, block, 0, stream>>>(img, gui, est, var, out);
}

// Round 17
// 25.292 us; speedup vs baseline: 3.5839x; 3.5839x over previous
//
#include <hip/hip_runtime.h>

#define HH 64
#define WW 64
#define TT 16
#define NPIX (HH * WW * TT)   // 65536
#define HALO 10               // 4 + 2*3
#define HWH  (HALO * HALO)    // 100 halo (h,w) positions
#define CH_SZ (HWH * TT)      // 1600 floats per channel
#define NCH 15                // gui(9, sqrt-sigma-prescaled) + est(3) + var(3)

// lane i <- lane i-1 within 16-lane DPP rows (row_shr:1), 0-fill at row start.
__device__ __forceinline__ float dpp_up1(float x) {
    return __int_as_float(__builtin_amdgcn_update_dpp(
        0, __float_as_int(x), 0x111, 0xF, 0xF, true));
}
// lane i <- lane i+1 within 16-lane DPP rows (row_shl:1), 0-fill at row end.
__device__ __forceinline__ float dpp_dn1(float x) {
    return __int_as_float(__builtin_amdgcn_update_dpp(
        0, __float_as_int(x), 0x101, 0xF, 0xF, true));
}

// R9's proven structure (grid 256 x block 1024, 96KB f32 LDS, 1 block/CU,
// img global, K=2 + DPP, 16 waves = 2 pixel-groups x 8 column-splits;
// passed + replay-stable at 28.7us, VGPR 32, no spill) with two trims that
// each survived full validation elsewhere:
//  (1) gui stored PRESCALED by sqrt(SIG) at staging -> bilateral inner op
//      is d=ce-nv; fmaf(d,d,sb)  (R14: absmax unchanged by prescale)
//  (2) membership = (d2==0) | (d2<G2*V & vce!=0 & vnv!=0)  (case-verified
//      == reference; replay-validated in R15's full pass)
// R16's 2-blocks/CU f16 config diverged on replay -> quarantined.
__global__ __launch_bounds__(1024, 4) void statdenoise_kernel(
    const float* __restrict__ img,
    const float* __restrict__ gui,
    const float* __restrict__ est,
    const float* __restrict__ var,
    float* __restrict__ out)
{
    __shared__ float smem[NCH * CH_SZ];   // 96 KB; aliased by reduction later

    const float SQS[9] = {0.31622776601683794f, 0.31622776601683794f, 0.31622776601683794f,
                          7.0710678118654755f,  7.0710678118654755f,  7.0710678118654755f,
                          3.1622776601683795f,  3.1622776601683795f,  3.1622776601683795f};
    const float G2 = 2.907f * 2.907f;   // gamma^2

    const int tid  = threadIdx.x;
    const int lane = tid & 63;
    const int sw   = tid >> 6;      // wave 0..15
    const int s7   = sw & 7;        // column-split 0..7
    const int pg   = sw >> 3;       // pixel-group 0..1
    const int tg   = lane & 7;      // t-group 0..7
    const int hwl  = lane >> 3;     // 0..7
    const int t0   = tg * 2;        // owns t0, t0+1
    const int h0   = (blockIdx.x >> 4) << 2;   // tile origin
    const int w0   = (blockIdx.x & 15) << 2;

    // ---- stage 15 channels of the 10x10x16 halo (edge-clamped; OOB
    //      values masked later by inb, exactly as the clamped loads) ----
#pragma unroll
    for (int rep = 0; rep < 2; ++rep) {
        const int q = tid + rep * 1024;
        if (q < CH_SZ) {
            const int t   = q & 15;
            const int hwq = q >> 4;                  // 0..99
            const int hq  = (hwq * 205) >> 11;       // exact /10 for hwq<1024
            const int wq  = hwq - hq * 10;
            const int hs  = min(max(h0 - 3 + hq, 0), HH - 1);
            const int ws  = min(max(w0 - 3 + wq, 0), WW - 1);
            const int g   = (((hs << 6) + ws) << 4) + t;
#pragma unroll
            for (int c = 0; c < 9; ++c)
                smem[c * CH_SZ + q] = gui[c * NPIX + g] * SQS[c];   // prescaled
#pragma unroll
            for (int c = 0; c < 3; ++c) {
                smem[(9 + c)  * CH_SZ + q] = est[c * NPIX + g];
                smem[(12 + c) * CH_SZ + q] = var[c * NPIX + g];
            }
        }
    }
    __syncthreads();

    const int pidx = pg * 8 + hwl;        // tile pixel 0..15
    const int th = pidx >> 2, tw = pidx & 3;
    const int hg = h0 + th,  wg = w0 + tw;

    // center values from LDS (center is inside the halo)
    const int lc = (((th + 3) * 10) + (tw + 3)) * 16 + t0;
    float2 gc[9];
#pragma unroll
    for (int c = 0; c < 9; ++c) gc[c] = *(const float2*)&smem[c * CH_SZ + lc];
    float2 ec[3], vc[3];
#pragma unroll
    for (int c = 0; c < 3; ++c) {
        ec[c] = *(const float2*)&smem[(9 + c)  * CH_SZ + lc];
        vc[c] = *(const float2*)&smem[(12 + c) * CH_SZ + lc];
    }

    const bool vLo = (t0 != 0);    // dt=-1 valid; also masks DPP boundary garbage
    const bool vHi = (t0 != 14);   // dt=+1 valid; also masks DPP boundary garbage

    float acc[2][4] = {};   // per owned t: {r,g,b,wsum}

    int dh = s7 / 7 - 3, dw = s7 % 7 - 3;   // column r = s7, then += 8
    for (int r = s7; r < 49; r += 8) {
        // halo coords are ALWAYS in range: th+dh+3 in [0,9], tw+dw+3 in [0,9]
        const int lb  = ((th + dh + 3) * 10 + (tw + dw + 3)) * 16 + t0;
        const bool inb = ((unsigned)(hg + dh) < (unsigned)HH) &
                         ((unsigned)(wg + dw) < (unsigned)WW);
        // clamped global offset for img
        const int hhc = min(max(hg + dh, 0), HH - 1);
        const int wwc = min(max(wg + dw, 0), WW - 1);
        const int gnb = (((hhc << 6) + wwc) << 4) + t0;

        // ---- bilateral over 9 prescaled guidance channels, 6 pairs ----
        float sb[2][3] = {};
#pragma unroll
        for (int c = 0; c < 9; ++c) {
            float2 m = *(const float2*)&smem[c * CH_SZ + lb];
            float nv[4] = {dpp_up1(m.y), m.x, m.y, dpp_dn1(m.x)};   // t0-1..t0+2
#pragma unroll
            for (int e = 0; e < 2; ++e) {
                float ce = e ? gc[c].y : gc[c].x;
#pragma unroll
                for (int k = 0; k < 3; ++k) {
                    float d = ce - nv[e + k];
                    sb[e][k] = fmaf(d, d, sb[e][k]);   // sig folded into inputs
                }
            }
        }

        // ---- membership (division-free Welch t-test, simplified) ----
        // mem = (d2==0) | (d2 < G2*V & vce!=0 & vnv!=0). Case-verified vs
        // reference (incl. v==0 kills and num==den==0 -> 0.5 -> member).
        // OOB h/w neighbors provably get weight 0 -> masked by inb.
        bool mem[2][3] = {{true, true, true}, {true, true, true}};
#pragma unroll
        for (int c = 0; c < 3; ++c) {
            float2 em = *(const float2*)&smem[(9 + c)  * CH_SZ + lb];
            float2 vm = *(const float2*)&smem[(12 + c) * CH_SZ + lb];
            float env[4] = {dpp_up1(em.y), em.x, em.y, dpp_dn1(em.x)};
            float vnv[4] = {dpp_up1(vm.y), vm.x, vm.y, dpp_dn1(vm.x)};
#pragma unroll
            for (int e = 0; e < 2; ++e) {
                float ece = e ? ec[c].y : ec[c].x;
                float vce = e ? vc[c].y : vc[c].x;
#pragma unroll
                for (int k = 0; k < 3; ++k) {
                    float d  = ece - env[e + k];
                    float d2 = d * d;
                    float V  = vce + vnv[e + k];
                    bool ok = (d2 == 0.f) |
                              ((d2 < G2 * V) & !((vce == 0.f) | (vnv[e + k] == 0.f)));
                    mem[e][k] = mem[e][k] & ok;
                }
            }
        }

        // ---- weights ----
        float wt[2][3];
#pragma unroll
        for (int e = 0; e < 2; ++e) {
#pragma unroll
            for (int k = 0; k < 3; ++k) {
                bool ok = inb && mem[e][k];
                if (e == 0 && k == 0) ok = ok && vLo;   // tt = t0-1
                if (e == 1 && k == 2) ok = ok && vHi;   // tt = t0+2
                wt[e][k] = ok ? __expf(-0.5f * sb[e][k]) : 0.f;
            }
        }

        // ---- accumulate image (global path; consumed last, latency hidden) ----
#pragma unroll
        for (int c = 0; c < 3; ++c) {
            float2 im = *(const float2*)&img[c * NPIX + gnb];
            float iv[4] = {dpp_up1(im.y), im.x, im.y, dpp_dn1(im.x)};
#pragma unroll
            for (int e = 0; e < 2; ++e) {
                acc[e][c] = fmaf(wt[e][0], iv[e],
                            fmaf(wt[e][1], iv[e + 1],
                            fmaf(wt[e][2], iv[e + 2], acc[e][c])));
            }
        }
#pragma unroll
        for (int e = 0; e < 2; ++e)
            acc[e][3] += wt[e][0] + wt[e][1] + wt[e][2];

        dw += 8;
        while (dw > 3) { dw -= 7; ++dh; }
    }

    // ---- combine the 8 splits (alias staging LDS after all reads done) ----
    __syncthreads();
    float4* red = (float4*)smem;          // 2048 x float4 = 32 KB < 96 KB
    red[(sw * 64 + lane) * 2 + 0] = make_float4(acc[0][0], acc[0][1], acc[0][2], acc[0][3]);
    red[(sw * 64 + lane) * 2 + 1] = make_float4(acc[1][0], acc[1][1], acc[1][2], acc[1][3]);
    __syncthreads();

    if (tid < 256) {
        const int pg_ = tid >> 7, hwl_ = (tid >> 4) & 7, tg_ = (tid >> 1) & 7, e_ = tid & 1;
        float4 sum = make_float4(0.f, 0.f, 0.f, 0.f);
#pragma unroll
        for (int q = 0; q < 8; ++q) {
            const int swq = pg_ * 8 + q;
            float4 v = red[(swq * 64 + hwl_ * 8 + tg_) * 2 + e_];
            sum.x += v.x; sum.y += v.y; sum.z += v.z; sum.w += v.w;
        }
        const int pidx_ = pg_ * 8 + hwl_;
        const int th_ = pidx_ >> 2, tw_ = pidx_ & 3;
        const int px = ((((h0 + th_) << 6) + (w0 + tw_)) << 4) + tg_ * 2 + e_;
        const float inv = 1.f / sum.w;    // wsum >= 1 (center weight == 1)
        out[0 * NPIX + px] = sum.x * inv;
        out[1 * NPIX + px] = sum.y * inv;
        out[2 * NPIX + px] = sum.z * inv;
    }
}

extern "C" void kernel_launch(void* const* d_in, const int* in_sizes, int n_in,
                              void* d_out, int out_size, void* d_ws, size_t ws_size,
                              hipStream_t stream) {
    const float* img = (const float*)d_in[0];
    const float* gui = (const float*)d_in[1];
    const float* est = (const float*)d_in[2];
    const float* var = (const float*)d_in[3];
    float* out = (float*)d_out;

    dim3 grid(256);     // one 4x4x16 tile per block, 1 block per CU
    dim3 block(1024);   // 16 waves: 2 pixel-groups x 8 column-splits
    statdenoise_kernel<<<grid, block, 0, stream>>>(img, gui, est, var, out);
}